// Round 7
// baseline (311.432 us; speedup 1.0000x reference)
//
#include <hip/hip_runtime.h>
#include <cstdint>
#include <cstddef>

// ---------------------------------------------------------------------------
// ReweightGNN: 3x GraphSAGE-reweight (lmda=1.0) + dropout(0.5) + 2-layer MLP
// N=50000, E=800000, D=128, DOUT=10. Outputs: h [N,128] fp32, y [N,10] fp32.
// R16 (from verified R15): agg FUSED into the layer GEMM.
//   Each 128-row block: (1) gather/aggregate its rows into LDS AggT[128][136]
//   (R12-verified wave loop, bf16 values identical to the old aggb path),
//   (2) K=256 MFMA loop, kb<128 read from AggT, kb>=128 staged from Hin.
//   Removes 3 agg dispatches + aggb round-trip; gather pipelines against
//   MFMA across blocks. sw recomputed block-locally (depends only on ew,invc)
//   -> swv gone. Riders: mw0 on scatter, mw1 on fused1, mw2 on fused2.
//   mlp still fused into layer-3 (tT aliases AggT after all MFMA reads done).
// ---------------------------------------------------------------------------

#define N_NODES 50000
#define N_EDGES 800000
#define DGN 128
#define DOUT 10
#define NELEM (N_NODES * DGN)       // 6,400,000
#define NMASKW (NELEM / 64)         // 100,000 uint64 words per mask
#define NBINS 391                   // ceil(50000/128) coarse bins (row>>7)
#define TILE 4096                   // edges per scatter block
#define BSTR 4096                   // pk entries reserved per bin
#define NTILES ((N_EDGES + TILE - 1) / TILE)   // 196
#define GB128 ((N_NODES + 127) / 128)   // 391 fused blocks (128 rows)
#define MK_BLOCKS 25000             // 256-thread rider blocks (scatter host)
#define MKB512 12500                // 512-thread rider blocks (fused hosts)

// mega-kernel block ranges (no masks)
#define XB_BLK 6250                 // x fp32->bf16 (1.6M float4)
#define HI_BLK NTILES
#define WC_BLK 128
#define TR_BLK 192
#define R0 XB_BLK
#define R1 (R0 + HI_BLK)
#define R2 (R1 + WC_BLK)
#define R3 (R2 + TR_BLK)
#define MEGA_BLOCKS (R3 + 1)

typedef __attribute__((ext_vector_type(8))) short bf16x8;
typedef __attribute__((ext_vector_type(4))) float f32x4;

__host__ __device__ static inline unsigned short f2bf(float f) {
  union { float f; unsigned u; } c; c.f = f;
  unsigned u = c.u;
  return (unsigned short)((u + 0x7fffu + ((u >> 16) & 1u)) >> 16);  // RNE
}
__device__ static inline float bflo(unsigned u) { return __uint_as_float(u << 16); }
__device__ static inline float bfhi(unsigned u) { return __uint_as_float(u & 0xffff0000u); }

// ---------------------------------------------------------------------------
// threefry2x32 (exact JAX)
// ---------------------------------------------------------------------------
__host__ __device__ static inline void tf2x32(unsigned k0, unsigned k1,
                                              unsigned c0, unsigned c1,
                                              unsigned& o0, unsigned& o1) {
  unsigned ks2 = k0 ^ k1 ^ 0x1BD11BDAu;
  unsigned x0 = c0 + k0;
  unsigned x1 = c1 + k1;
#define TFR(r) { x0 += x1; x1 = (x1 << (r)) | (x1 >> (32 - (r))); x1 ^= x0; }
  TFR(13) TFR(15) TFR(26) TFR(6)
  x0 += k1;  x1 += ks2 + 1u;
  TFR(17) TFR(29) TFR(16) TFR(24)
  x0 += ks2; x1 += k0 + 2u;
  TFR(13) TFR(15) TFR(26) TFR(6)
  x0 += k0;  x1 += k1 + 3u;
  TFR(17) TFR(29) TFR(16) TFR(24)
  x0 += k1;  x1 += ks2 + 4u;
  TFR(13) TFR(15) TFR(26) TFR(6)
  x0 += ks2; x1 += k0 + 5u;
#undef TFR
  o0 = x0; o1 = x1;
}

// one bit-packed mask stream chunk (rider blocks use this)
__device__ static inline void mask_chunk(unsigned long long* __restrict__ gm,
                                         int i, unsigned k0, unsigned k1) {
  unsigned o0, o1;
  tf2x32(k0, k1, 0u, (unsigned)i, o0, o1);
  unsigned long long b = __ballot(((o0 ^ o1) >> 31) == 0u);
  if ((threadIdx.x & 63) == 0) gm[i >> 6] = b;
}

// ---------------------------------------------------------------------------
// Mega prep kernel: x convert | hist | W_comb | transposes | bvec
// ---------------------------------------------------------------------------
__global__ __launch_bounds__(256) void mega_kernel(
    const float* __restrict__ x, unsigned short* __restrict__ xb,
    const int* __restrict__ ei, int* __restrict__ chist,
    const float* __restrict__ Wli, const float* __restrict__ Wai,
    const float* __restrict__ Wlh, const float* __restrict__ Wah,
    const float* __restrict__ Wm1,
    const float* __restrict__ bli, const float* __restrict__ blh,
    unsigned short* __restrict__ Tai, unsigned short* __restrict__ Tah,
    unsigned short* __restrict__ Tm1,
    float* __restrict__ bvi, float* __restrict__ bvh) {
  __shared__ int h[NBINS];
  const int b = blockIdx.x;
  const int tid = threadIdx.x;

  if (b < R0) {                       // ---- x convert ----
    int g = b * 256 + tid;
    float4 v = ((const float4*)x)[g];
    ushort4 o;
    o.x = f2bf(v.x); o.y = f2bf(v.y); o.z = f2bf(v.z); o.w = f2bf(v.w);
    ((ushort4*)xb)[g] = o;
  } else if (b < R1) {                // ---- hist ----
    for (int i = tid; i < NBINS; i += 256) h[i] = 0;
    __syncthreads();
    const int e0 = (b - R0) * TILE;
#pragma unroll 4
    for (int j = 0; j < TILE; j += 256) {
      int e = e0 + j + tid;
      if (e < N_EDGES) {
        int r = ei[e];
        r = (r < 0) ? 0 : (r >= N_NODES ? N_NODES - 1 : r);
        atomicAdd(&h[r >> 7], 1);
      }
    }
    __syncthreads();
    for (int i = tid; i < NBINS; i += 256)
      if (h[i]) atomicAdd(&chist[i], h[i]);
  } else if (b < R2) {                // ---- W_comb (fp32 accumulate) ----
    int idx = (b - R1) * 256 + tid;   // [0, 32768)
    int n = idx & 127;
    int k = (idx >> 7) & 127;
    int m = idx >> 14;                // 0: in-layer, 1: hidden
    const float* Wl = m ? Wlh : Wli;
    const float* Wa = m ? Wah : Wai;
    unsigned short* T = m ? Tah : Tai;
    float acc = 0.0f;
#pragma unroll 8
    for (int j = 0; j < 128; ++j)
      acc += Wl[k * 128 + j] * Wa[j * 128 + n];
    T[n * 256 + k] = f2bf(acc);
  } else if (b < R3) {                // ---- transposes ----
    int j = (b - R2) * 256 + tid;     // [0, 49152)
    if (j < 16384) {
      int kk = j & 127, n = j >> 7;
      Tai[n * 256 + 128 + kk] = f2bf(Wai[(size_t)(128 + kk) * 128 + n]);
    } else if (j < 32768) {
      int q = j - 16384;
      int kk = q & 127, n = q >> 7;
      Tah[n * 256 + 128 + kk] = f2bf(Wah[(size_t)(128 + kk) * 128 + n]);
    } else {
      int q = j - 32768;
      int k = q & 127, n = q >> 7;
      Tm1[n * 128 + k] = f2bf(Wm1[(size_t)k * 128 + n]);
    }
  } else {                            // ---- bvec ----
    int n = tid & 127;
    const float* bl = (tid < 128) ? bli : blh;
    const float* Wa = (tid < 128) ? Wai : Wah;
    float acc = 0.0f;
    for (int j = 0; j < 128; ++j) acc += bl[j] * Wa[j * 128 + n];
    if (tid < 128) bvi[n] = acc; else bvh[n] = acc;
  }
}

// ---------------------------------------------------------------------------
// CSR build. scatter hosts mw0 riders; fixed 4096-entry pk bins (0-based
// ccursor, memset init). place computes CSR base via chist block reduction.
// ---------------------------------------------------------------------------
__global__ __launch_bounds__(256) void scatter_kernel(const int* __restrict__ ei,
                                                      const float* __restrict__ ew,
                                                      int* __restrict__ ccursor,
                                                      uint2* __restrict__ pk,
                                                      unsigned long long* __restrict__ mg0,
                                                      unsigned k00, unsigned k01) {
  if (blockIdx.x >= NTILES) {          // ---- mw0 rider blocks ----
    mask_chunk(mg0, (blockIdx.x - NTILES) * 256 + threadIdx.x, k00, k01);
    return;
  }
  __shared__ uint2 st[TILE];
  __shared__ unsigned short sbin[TILE];
  __shared__ int h[NBINS];
  __shared__ int base[NBINS];
  __shared__ int gbase[NBINS];
  __shared__ int cur[NBINS];
  __shared__ int sc[512];
  const int tid = threadIdx.x;
  const int e0 = blockIdx.x * TILE;
  const int nt = (N_EDGES - e0 < TILE) ? (N_EDGES - e0) : TILE;

  for (int i = tid; i < NBINS; i += 256) { h[i] = 0; cur[i] = 0; }
  __syncthreads();
  for (int j = tid; j < nt; j += 256) {
    int r = ei[e0 + j];
    r = (r < 0) ? 0 : (r >= N_NODES ? N_NODES - 1 : r);
    atomicAdd(&h[r >> 7], 1);
  }
  __syncthreads();
  sc[tid] = (tid < NBINS) ? h[tid] : 0;
  sc[tid + 256] = (tid + 256 < NBINS) ? h[tid + 256] : 0;
  __syncthreads();
  for (int off = 1; off < 512; off <<= 1) {
    int a0 = (tid >= off) ? sc[tid - off] : 0;
    int a1 = (tid + 256 >= off) ? sc[tid + 256 - off] : 0;
    __syncthreads();
    sc[tid] += a0; sc[tid + 256] += a1;
    __syncthreads();
  }
  if (tid < NBINS) {
    base[tid] = sc[tid] - h[tid];
    if (h[tid]) gbase[tid] = tid * BSTR + atomicAdd(&ccursor[tid], h[tid]);
  }
  if (tid + 256 < NBINS) {
    base[tid + 256] = sc[tid + 256] - h[tid + 256];
    if (h[tid + 256])
      gbase[tid + 256] = (tid + 256) * BSTR + atomicAdd(&ccursor[tid + 256], h[tid + 256]);
  }
  __syncthreads();
  for (int j = tid; j < nt; j += 256) {
    int r = ei[e0 + j];
    r = (r < 0) ? 0 : (r >= N_NODES ? N_NODES - 1 : r);
    int c = ei[N_EDGES + e0 + j];
    c = (c < 0) ? 0 : (c >= N_NODES ? N_NODES - 1 : c);
    int bb = r >> 7;
    int slot = base[bb] + atomicAdd(&cur[bb], 1);
    uint2 p;
    p.x = ((unsigned)r << 16) | (unsigned)c;
    p.y = __float_as_uint(ew[e0 + j]);
    st[slot] = p;
    sbin[slot] = (unsigned short)bb;
  }
  __syncthreads();
  for (int j = tid; j < nt; j += 256) {
    int bb = sbin[j];
    pk[(size_t)gbase[bb] + (j - base[bb])] = st[j];
  }
}

__global__ __launch_bounds__(256) void place_kernel(const int* __restrict__ chist,
                                                    const uint2* __restrict__ pk,
                                                    uint2* __restrict__ csr,
                                                    int* __restrict__ rowptr,
                                                    float* __restrict__ invc) {
  __shared__ int red[256];
  __shared__ int lcnt[128];
  __shared__ int lpre[128];
  __shared__ int lcur[128];
  __shared__ int sc[128];
  const int b = blockIdx.x;
  const int tid = threadIdx.x;

  int psum = 0;
  for (int i = tid; i < b; i += 256) psum += chist[i];
  red[tid] = psum;
  __syncthreads();
  for (int off = 128; off > 0; off >>= 1) {
    if (tid < off) red[tid] += red[tid + off];
    __syncthreads();
  }
  const int cb = red[0];
  const int n = chist[b];
  const uint2* __restrict__ pkb = pk + (size_t)b * BSTR;
  const int r0 = b << 7;
  const int nr = (N_NODES - r0 < 128) ? (N_NODES - r0) : 128;

  if (tid < 128) { lcnt[tid] = 0; lcur[tid] = 0; }
  __syncthreads();
  for (int i = tid; i < n; i += 256) {
    int r7 = (int)(pkb[i].x >> 16) - r0;
    atomicAdd(&lcnt[r7], 1);
  }
  __syncthreads();
  if (tid < 128) sc[tid] = lcnt[tid];
  __syncthreads();
  for (int off = 1; off < 128; off <<= 1) {
    int tv = (tid >= off && tid < 128) ? sc[tid - off] : 0;
    __syncthreads();
    if (tid < 128) sc[tid] += tv;
    __syncthreads();
  }
  if (tid < 128) lpre[tid] = sc[tid] - lcnt[tid];
  __syncthreads();
  if (tid < nr) {
    rowptr[r0 + tid] = cb + lpre[tid];
    int c = lcnt[tid];
    invc[r0 + tid] = 1.0f / (float)(c > 1 ? c : 1);
  }
  if (b == NBINS - 1 && tid == 0) rowptr[N_NODES] = N_EDGES;
  for (int i = tid; i < n; i += 256) {
    uint2 p = pkb[i];
    int r7 = (int)(p.x >> 16) - r0;
    int slot = cb + lpre[r7] + atomicAdd(&lcur[r7], 1);
    uint2 o;
    o.x = p.x & 0xFFFFu;
    o.y = p.y;
    csr[slot] = o;
  }
}

// ---------------------------------------------------------------------------
// Fused layer kernel (R16): 512 threads, 128 rows per block.
// Phase 1 (agg): wave wid aggregates rows m0+wid*16..+15 into LDS
// AggT[128][136] bf16 + sws[128] (R12-verified inner loop: coalesced 8B/lane
// CSR preload, UNCONDITIONAL __shfl broadcasts, ok-mask VALU select, 4 edges
// x 16 dim-lanes, shfl_xor reduce; f2bf packing identical to old aggb path).
// Phase 2 (GEMM): K=256; kb<128 A-fragments read from AggT, kb>=128 staged
// from Hin into Als. 8 waves (4wm x 2wn), per-wave 32x64 = 2x4 MFMA 16x16x32.
// Epilogue: +sws*bvec+bagg, ReLU, bit-packed dropout, bf16/fp32 store.
// MASKGEN: blocks >= GB128 generate one threefry mask stream.
// MLP (layer 3): h-tile -> tT (aliases AggT; all AggT MFMA reads done),
// t = relu(h @ Tm1 + b1) via MFMA, y = t @ W2 + b2 via MFMA (Wsb bf16 LDS).
// ---------------------------------------------------------------------------
template <bool WF32, bool MASKGEN, bool MLP>
__global__ __launch_bounds__(512) void layer_fused(
    const unsigned short* __restrict__ Hin,   // gather table [N][128] bf16
    const int* __restrict__ rowptr,
    const uint2* __restrict__ csr,
    const float* __restrict__ invc,
    const unsigned short* __restrict__ Wt,    // [128 cols][256 k] bf16
    const float* __restrict__ bvec, const float* __restrict__ bagg,
    const unsigned long long* __restrict__ maskw,
    float* __restrict__ outf, unsigned short* __restrict__ outb,
    unsigned long long* __restrict__ gm, unsigned gk0, unsigned gk1,
    const unsigned short* __restrict__ Wt2,   // Tm1 [128 cols][128 k] (MLP)
    const float* __restrict__ b1,
    const float* __restrict__ W2, const float* __restrict__ b2,
    float* __restrict__ y) {
  if (MASKGEN && blockIdx.x >= GB128) {
    mask_chunk(gm, (blockIdx.x - GB128) * 512 + threadIdx.x, gk0, gk1);
    return;
  }
  constexpr int LS = 72;
  constexpr int LT = 136;                      // 272B row stride (16B-aligned)
  __shared__ unsigned short AggT[128 * LT];    // 34.8 KB; reused as tT (MLP)
  __shared__ unsigned short Als[128 * LS];     // 18.4 KB (Hin k-slices)
  __shared__ unsigned short Bls[128 * LS];     // 18.4 KB
  __shared__ unsigned short Wsb[MLP ? 16 * LT : 2];   // 4.3 KB (MLP only)
  __shared__ float bs[MLP ? DOUT : 1];
  __shared__ float sws[128];
  const int tid = threadIdx.x;
  const int m0 = blockIdx.x * 128;
  const int lane = tid & 63;
  const int wid = tid >> 6;                 // 0..7
  const int wm = (wid >> 1) * 32;           // 0,32,64,96
  const int wn = (wid & 1) * 64;            // 0,64
  const int ln = lane & 15;
  const int lh = lane >> 4;
  const int sArow = tid >> 2;               // 0..127 (col for B staging)
  const int sAk = (tid & 3) * 16;
  int arow = m0 + sArow;
  if (arow >= N_NODES) arow = N_NODES - 1;

  if (MLP) {
    for (int i = tid; i < 16 * 128; i += 512) {
      int c = i >> 7, k = i & 127;
      Wsb[c * LT + k] = (c < DOUT) ? f2bf(W2[(size_t)k * DOUT + c]) : (unsigned short)0;
    }
    if (tid < DOUT) bs[tid] = b2[tid];
  }

  // ---- Phase 1: aggregate 16 rows per wave into AggT + sws ----
  {
    const uint4* __restrict__ H = (const uint4*)Hin;   // 16 uint4 per row
    const int es = lane >> 4;
    const int cg = lane & 15;
    for (int t = 0; t < 16; ++t) {
      const int rl = wid * 16 + t;
      const int r = m0 + rl;
      int start = 0, num = 0;
      if (r < N_NODES) { start = rowptr[r]; num = rowptr[r + 1] - start; }
      int qi = (num > 0) ? (start + (lane < num ? lane : num - 1)) : 0;
      uint2 myq = csr[qi];
      float a[8] = {0.f, 0.f, 0.f, 0.f, 0.f, 0.f, 0.f, 0.f};
      float ws = 0.f;
      const int nbv = (num < 64) ? num : 64;
      for (int e = 0; e < nbv; e += 16) {
#pragma unroll
        for (int j = 0; j < 4; ++j) {
          int idx = e + j * 4 + es;
          bool ok = idx < nbv;
          int sl = ok ? idx : nbv - 1;
          // UNCONDITIONAL convergent shfls (R11 post-mortem)
          int c0 = __shfl((int)myq.x, sl);
          int w0 = __shfl((int)myq.y, sl);
          unsigned col = (unsigned)c0;
          float w = ok ? __uint_as_float((unsigned)w0) : 0.0f;
          uint4 p = H[(size_t)col * 16 + cg];
          ws += w;
          a[0] += w * bflo(p.x); a[1] += w * bfhi(p.x);
          a[2] += w * bflo(p.y); a[3] += w * bfhi(p.y);
          a[4] += w * bflo(p.z); a[5] += w * bfhi(p.z);
          a[6] += w * bflo(p.w); a[7] += w * bfhi(p.w);
        }
      }
      for (int e = 64; e < num; e += 16) {   // rare tail: degree > 64
#pragma unroll
        for (int j = 0; j < 4; ++j) {
          int idx = e + j * 4 + es;
          bool ok = idx < num;
          int idxc = ok ? idx : (num - 1);
          uint2 q = csr[start + idxc];
          float w = ok ? __uint_as_float(q.y) : 0.0f;
          uint4 p = H[(size_t)q.x * 16 + cg];
          ws += w;
          a[0] += w * bflo(p.x); a[1] += w * bfhi(p.x);
          a[2] += w * bflo(p.y); a[3] += w * bfhi(p.y);
          a[4] += w * bflo(p.z); a[5] += w * bfhi(p.z);
          a[6] += w * bflo(p.w); a[7] += w * bfhi(p.w);
        }
      }
#pragma unroll
      for (int k = 0; k < 8; ++k) {
        a[k] += __shfl_xor(a[k], 32);
        a[k] += __shfl_xor(a[k], 16);
      }
      ws += __shfl_xor(ws, 32);
      ws += __shfl_xor(ws, 16);
      const float s = (r < N_NODES) ? invc[r] : 0.0f;
      if (es == 0) {
        uint4 o;
        o.x = (unsigned)f2bf(a[0] * s) | ((unsigned)f2bf(a[1] * s) << 16);
        o.y = (unsigned)f2bf(a[2] * s) | ((unsigned)f2bf(a[3] * s) << 16);
        o.z = (unsigned)f2bf(a[4] * s) | ((unsigned)f2bf(a[5] * s) << 16);
        o.w = (unsigned)f2bf(a[6] * s) | ((unsigned)f2bf(a[7] * s) << 16);
        *(uint4*)&AggT[rl * LT + cg * 8] = o;
      }
      if (lane == 0) sws[rl] = ws * s;
    }
  }

  // ---- Phase 2: GEMM K=256 over [AggT | Hin] @ Wt ----
  f32x4 acc[2][4];
#pragma unroll
  for (int i = 0; i < 2; ++i)
#pragma unroll
    for (int j = 0; j < 4; ++j)
#pragma unroll
      for (int r = 0; r < 4; ++r) acc[i][j][r] = 0.0f;

  for (int kb = 0; kb < 256; kb += 64) {
    if (kb >= 128) {
      const unsigned short* ap = Hin + (size_t)arow * 128 + (kb & 127) + sAk;
      unsigned short* al = &Als[sArow * LS + sAk];
      *(uint4*)(al + 0) = *(const uint4*)(ap + 0);
      *(uint4*)(al + 8) = *(const uint4*)(ap + 8);
    }
    const unsigned short* bp = Wt + (size_t)sArow * 256 + kb + sAk;
    unsigned short* bl = &Bls[sArow * LS + sAk];
    *(uint4*)(bl + 0) = *(const uint4*)(bp + 0);
    *(uint4*)(bl + 8) = *(const uint4*)(bp + 8);
    __syncthreads();   // kb=0: also orders Phase-1 AggT/sws writes vs reads
#pragma unroll
    for (int ks = 0; ks < 64; ks += 32) {
      bf16x8 af[2], bfr[4];
#pragma unroll
      for (int i = 0; i < 2; ++i)
        af[i] = (kb < 128)
            ? *(const bf16x8*)&AggT[(wm + i * 16 + ln) * LT + kb + ks + lh * 8]
            : *(const bf16x8*)&Als[(wm + i * 16 + ln) * LS + ks + lh * 8];
#pragma unroll
      for (int j = 0; j < 4; ++j)
        bfr[j] = *(const bf16x8*)&Bls[(wn + j * 16 + ln) * LS + ks + lh * 8];
#pragma unroll
      for (int i = 0; i < 2; ++i)
#pragma unroll
        for (int j = 0; j < 4; ++j)
          acc[i][j] = __builtin_amdgcn_mfma_f32_16x16x32_bf16(af[i], bfr[j], acc[i][j], 0, 0, 0);
    }
    __syncthreads();
  }

  // epilogue: C/D map col=lane&15, row=(lane>>4)*4+reg  [m89/m91]
  const int lm = lane >> 4;
  float bc[4], b2c[4];
#pragma unroll
  for (int j = 0; j < 4; ++j) {
    int col = wn + j * 16 + ln;
    bc[j] = bvec[col];
    b2c[j] = bagg[col];
  }
#pragma unroll
  for (int i = 0; i < 2; ++i) {
    const int lr0 = wm + i * 16 + lm * 4;
#pragma unroll
    for (int r = 0; r < 4; ++r) {
      const int row = m0 + lr0 + r;
      if (row >= N_NODES) continue;
      const float swr = sws[lr0 + r];
      const unsigned long long mw = maskw[(size_t)row * 2 + (wn >> 6)];
#pragma unroll
      for (int j = 0; j < 4; ++j) {
        const int col = wn + j * 16 + ln;
        float v = acc[i][j][r] + swr * bc[j] + b2c[j];
        v = fmaxf(v, 0.0f);
        v = ((mw >> (col & 63)) & 1ull) ? 2.0f * v : 0.0f;
        if (WF32) outf[(size_t)row * DGN + col] = v;
        if (MLP) AggT[(lr0 + r) * LT + col] = f2bf(v);   // tT aliases AggT
        else outb[(size_t)row * DGN + col] = f2bf(v);
      }
    }
  }

  if (MLP) {
    __syncthreads();   // tT complete; Bls free for Tm1

    f32x4 acc2[2][4];
#pragma unroll
    for (int i = 0; i < 2; ++i)
#pragma unroll
      for (int j = 0; j < 4; ++j)
#pragma unroll
        for (int r = 0; r < 4; ++r) acc2[i][j][r] = 0.0f;

    for (int kb = 0; kb < 128; kb += 64) {
      const unsigned short* bp = Wt2 + (size_t)sArow * 128 + kb + sAk;
      unsigned short* bl = &Bls[sArow * LS + sAk];
      *(uint4*)(bl + 0) = *(const uint4*)(bp + 0);
      *(uint4*)(bl + 8) = *(const uint4*)(bp + 8);
      __syncthreads();
#pragma unroll
      for (int ks = 0; ks < 64; ks += 32) {
        bf16x8 af[2], bfr[4];
#pragma unroll
        for (int i = 0; i < 2; ++i)
          af[i] = *(const bf16x8*)&AggT[(wm + i * 16 + ln) * LT + kb + ks + lh * 8];
#pragma unroll
        for (int j = 0; j < 4; ++j)
          bfr[j] = *(const bf16x8*)&Bls[(wn + j * 16 + ln) * LS + ks + lh * 8];
#pragma unroll
        for (int i = 0; i < 2; ++i)
#pragma unroll
          for (int j = 0; j < 4; ++j)
            acc2[i][j] = __builtin_amdgcn_mfma_f32_16x16x32_bf16(af[i], bfr[j], acc2[i][j], 0, 0, 0);
      }
      __syncthreads();
    }

    // epilogue2 -> t tile (overwrites AggT; all reads done)
    float bcol[4];
#pragma unroll
    for (int j = 0; j < 4; ++j) bcol[j] = b1[wn + j * 16 + ln];
#pragma unroll
    for (int i = 0; i < 2; ++i) {
      const int lr0 = wm + i * 16 + lm * 4;
#pragma unroll
      for (int r = 0; r < 4; ++r) {
        const int lr = lr0 + r;
#pragma unroll
        for (int j = 0; j < 4; ++j) {
          const int col = wn + j * 16 + ln;
          float v = fmaxf(acc2[i][j][r] + bcol[j], 0.0f);
          AggT[lr * LT + col] = f2bf(v);
        }
      }
    }
    __syncthreads();

    // mlp2 via MFMA: wave w handles rows w*16..w*16+15, cols 0..15 (10 used)
    f32x4 acc3;
#pragma unroll
    for (int r = 0; r < 4; ++r) acc3[r] = 0.0f;
#pragma unroll
    for (int kt = 0; kt < 4; ++kt) {
      bf16x8 af = *(const bf16x8*)&AggT[(wid * 16 + ln) * LT + kt * 32 + lh * 8];
      bf16x8 bw = *(const bf16x8*)&Wsb[ln * LT + kt * 32 + lh * 8];
      acc3 = __builtin_amdgcn_mfma_f32_16x16x32_bf16(af, bw, acc3, 0, 0, 0);
    }
    if (ln < DOUT) {
#pragma unroll
      for (int r = 0; r < 4; ++r) {
        const int row = m0 + wid * 16 + lm * 4 + r;
        if (row < N_NODES) y[(size_t)row * DOUT + ln] = acc3[r] + bs[ln];
      }
    }
  }
}

// ---------------------------------------------------------------------------
extern "C" void kernel_launch(void* const* d_in, const int* in_sizes, int n_in,
                              void* d_out, int out_size, void* d_ws, size_t ws_size,
                              hipStream_t stream) {
  const float* x        = (const float*)d_in[0];
  const int*   ei       = (const int*)d_in[1];
  const float* ew       = (const float*)d_in[2];
  const float* W_lin_in = (const float*)d_in[3];
  const float* b_lin_in = (const float*)d_in[4];
  const float* W_agg_in = (const float*)d_in[5];
  const float* b_agg_in = (const float*)d_in[6];
  const float* W_lin_h  = (const float*)d_in[7];
  const float* b_lin_h  = (const float*)d_in[8];
  const float* W_agg_h  = (const float*)d_in[9];
  const float* b_agg_h  = (const float*)d_in[10];
  const float* W_mlp1   = (const float*)d_in[11];
  const float* b_mlp1   = (const float*)d_in[12];
  const float* W_mlp2   = (const float*)d_in[13];
  const float* b_mlp2   = (const float*)d_in[14];

  float* hout = (float*)d_out;
  float* yout = hout + (size_t)NELEM;

  char* p = (char*)d_ws;
  auto alloc = [&](size_t bytes) {
    char* q = p;
    p += (bytes + 255) & ~(size_t)255;
    return q;
  };
  int*   chist   = (int*)alloc((size_t)(NBINS + 1) * 4);
  int*   ccursor = (int*)alloc((size_t)NBINS * 4);
  int*   rowptr  = (int*)alloc((size_t)(N_NODES + 1) * 4);
  float* invc    = (float*)alloc((size_t)N_NODES * 4);
  uint2* pk      = (uint2*)alloc((size_t)NBINS * BSTR * 8);
  uint2* csr     = (uint2*)alloc((size_t)N_EDGES * 8);
  unsigned short* xb   = (unsigned short*)alloc((size_t)NELEM * 2);
  unsigned short* hA   = (unsigned short*)alloc((size_t)NELEM * 2);
  unsigned short* hB   = (unsigned short*)alloc((size_t)NELEM * 2);
  unsigned long long* mw0 = (unsigned long long*)alloc((size_t)NMASKW * 8);
  unsigned long long* mw1 = (unsigned long long*)alloc((size_t)NMASKW * 8);
  unsigned long long* mw2 = (unsigned long long*)alloc((size_t)NMASKW * 8);
  unsigned short* Tai = (unsigned short*)alloc(32768 * 2);
  unsigned short* Tah = (unsigned short*)alloc(32768 * 2);
  unsigned short* Tm1 = (unsigned short*)alloc(16384 * 2);
  float* bvi = (float*)alloc(128 * 4);
  float* bvh = (float*)alloc(128 * 4);

  unsigned dk[3][2];
  for (unsigned i = 0; i < 3; ++i) tf2x32(0u, 42u, 0u, i, dk[i][0], dk[i][1]);

  // ---- prep ----
  hipMemsetAsync(chist, 0, (size_t)(NBINS + 1) * 4, stream);
  hipMemsetAsync(ccursor, 0, (size_t)NBINS * 4, stream);
  mega_kernel<<<MEGA_BLOCKS, 256, 0, stream>>>(
      x, xb, ei, chist, W_lin_in, W_agg_in, W_lin_h, W_agg_h, W_mlp1,
      b_lin_in, b_lin_h, Tai, Tah, Tm1, bvi, bvh);

  // ---- CSR build (+ mw0 riders on scatter) ----
  scatter_kernel<<<NTILES + MK_BLOCKS, 256, 0, stream>>>(
      ei, ew, ccursor, pk, mw0, dk[0][0], dk[0][1]);
  place_kernel<<<NBINS, 256, 0, stream>>>(chist, pk, csr, rowptr, invc);

  // ---- layer 1 (fused agg+gemm, + mw1 riders) ----
  layer_fused<false, true, false><<<GB128 + MKB512, 512, 0, stream>>>(
      xb, rowptr, csr, invc, Tai, bvi, b_agg_in, mw0, nullptr, hA,
      mw1, dk[1][0], dk[1][1], nullptr, nullptr, nullptr, nullptr, nullptr);

  // ---- layer 2 (fused, + mw2 riders) ----
  layer_fused<false, true, false><<<GB128 + MKB512, 512, 0, stream>>>(
      hA, rowptr, csr, invc, Tah, bvh, b_agg_h, mw1, nullptr, hB,
      mw2, dk[2][0], dk[2][1], nullptr, nullptr, nullptr, nullptr, nullptr);

  // ---- layer 3 (fused + mlp) ----
  layer_fused<true, false, true><<<GB128, 512, 0, stream>>>(
      hB, rowptr, csr, invc, Tah, bvh, b_agg_h, mw2, hout, nullptr,
      nullptr, 0, 0, Tm1, b_mlp1, W_mlp2, b_mlp2, yout);
}

// Round 8
// 303.630 us; speedup vs baseline: 1.0257x; 1.0257x over previous
//
#include <hip/hip_runtime.h>
#include <cstdint>
#include <cstddef>

// ---------------------------------------------------------------------------
// ReweightGNN: 3x GraphSAGE-reweight (lmda=1.0) + dropout(0.5) + 2-layer MLP
// N=50000, E=800000, D=128, DOUT=10. Outputs: h [N,128] fp32, y [N,10] fp32.
// R17 = R15 (verified 295.8us; R16 fusion reverted — fused grid gives only
// ~12 gather waves/CU vs standalone agg's 32: gather is TLP/BW-bound at
// ~6.2 TB/s, fusion structurally starves it) plus:
//   (a) agg: wave-uniform j-group skip (nb is wave-uniform; skipped groups
//       contributed only w=0 terms — numerics identical, ~32% fewer issued
//       gather/FMA groups from Poisson(16) tails).
//   (b) hist folded into scatter (it already computes per-tile h[]); mega's
//       hist blocks removed.
// ---------------------------------------------------------------------------

#define N_NODES 50000
#define N_EDGES 800000
#define DGN 128
#define DOUT 10
#define NELEM (N_NODES * DGN)       // 6,400,000
#define NMASKW (NELEM / 64)         // 100,000 uint64 words per mask
#define NBINS 391                   // ceil(50000/128) coarse bins (row>>7)
#define TILE 4096                   // edges per scatter block
#define BSTR 4096                   // pk entries reserved per bin
#define NTILES ((N_EDGES + TILE - 1) / TILE)   // 196
#define GB128 ((N_NODES + 127) / 128)   // 391 gemm blocks (128 rows x 128 cols)
#define MK_BLOCKS 25000             // 256-thread rider blocks (scatter host)
#define MKB512 12500                // 512-thread rider blocks (gemm hosts)

// mega-kernel block ranges (hist removed — lives in scatter now)
#define XB_BLK 6250                 // x fp32->bf16 (1.6M float4)
#define WC_BLK 128
#define TR_BLK 192
#define R0 XB_BLK
#define R1 (R0 + WC_BLK)
#define R2 (R1 + TR_BLK)
#define MEGA_BLOCKS (R2 + 1)

#define AB_BLOCKS ((N_NODES + 3) / 4)   // 12500 agg blocks (4 rows each)

typedef __attribute__((ext_vector_type(8))) short bf16x8;
typedef __attribute__((ext_vector_type(4))) float f32x4;

__host__ __device__ static inline unsigned short f2bf(float f) {
  union { float f; unsigned u; } c; c.f = f;
  unsigned u = c.u;
  return (unsigned short)((u + 0x7fffu + ((u >> 16) & 1u)) >> 16);  // RNE
}
__device__ static inline float bflo(unsigned u) { return __uint_as_float(u << 16); }
__device__ static inline float bfhi(unsigned u) { return __uint_as_float(u & 0xffff0000u); }

// ---------------------------------------------------------------------------
// threefry2x32 (exact JAX)
// ---------------------------------------------------------------------------
__host__ __device__ static inline void tf2x32(unsigned k0, unsigned k1,
                                              unsigned c0, unsigned c1,
                                              unsigned& o0, unsigned& o1) {
  unsigned ks2 = k0 ^ k1 ^ 0x1BD11BDAu;
  unsigned x0 = c0 + k0;
  unsigned x1 = c1 + k1;
#define TFR(r) { x0 += x1; x1 = (x1 << (r)) | (x1 >> (32 - (r))); x1 ^= x0; }
  TFR(13) TFR(15) TFR(26) TFR(6)
  x0 += k1;  x1 += ks2 + 1u;
  TFR(17) TFR(29) TFR(16) TFR(24)
  x0 += ks2; x1 += k0 + 2u;
  TFR(13) TFR(15) TFR(26) TFR(6)
  x0 += k0;  x1 += k1 + 3u;
  TFR(17) TFR(29) TFR(16) TFR(24)
  x0 += k1;  x1 += ks2 + 4u;
  TFR(13) TFR(15) TFR(26) TFR(6)
  x0 += ks2; x1 += k0 + 5u;
#undef TFR
  o0 = x0; o1 = x1;
}

// one bit-packed mask stream chunk (rider blocks use this)
__device__ static inline void mask_chunk(unsigned long long* __restrict__ gm,
                                         int i, unsigned k0, unsigned k1) {
  unsigned o0, o1;
  tf2x32(k0, k1, 0u, (unsigned)i, o0, o1);
  unsigned long long b = __ballot(((o0 ^ o1) >> 31) == 0u);
  if ((threadIdx.x & 63) == 0) gm[i >> 6] = b;
}

// ---------------------------------------------------------------------------
// Mega prep kernel: x convert | W_comb | transposes | bvec
// ---------------------------------------------------------------------------
__global__ __launch_bounds__(256) void mega_kernel(
    const float* __restrict__ x, unsigned short* __restrict__ xb,
    const float* __restrict__ Wli, const float* __restrict__ Wai,
    const float* __restrict__ Wlh, const float* __restrict__ Wah,
    const float* __restrict__ Wm1,
    const float* __restrict__ bli, const float* __restrict__ blh,
    unsigned short* __restrict__ Tai, unsigned short* __restrict__ Tah,
    unsigned short* __restrict__ Tm1,
    float* __restrict__ bvi, float* __restrict__ bvh) {
  const int b = blockIdx.x;
  const int tid = threadIdx.x;

  if (b < R0) {                       // ---- x convert ----
    int g = b * 256 + tid;
    float4 v = ((const float4*)x)[g];
    ushort4 o;
    o.x = f2bf(v.x); o.y = f2bf(v.y); o.z = f2bf(v.z); o.w = f2bf(v.w);
    ((ushort4*)xb)[g] = o;
  } else if (b < R1) {                // ---- W_comb (fp32 accumulate) ----
    int idx = (b - R0) * 256 + tid;   // [0, 32768)
    int n = idx & 127;
    int k = (idx >> 7) & 127;
    int m = idx >> 14;                // 0: in-layer, 1: hidden
    const float* Wl = m ? Wlh : Wli;
    const float* Wa = m ? Wah : Wai;
    unsigned short* T = m ? Tah : Tai;
    float acc = 0.0f;
#pragma unroll 8
    for (int j = 0; j < 128; ++j)
      acc += Wl[k * 128 + j] * Wa[j * 128 + n];
    T[n * 256 + k] = f2bf(acc);
  } else if (b < R2) {                // ---- transposes ----
    int j = (b - R1) * 256 + tid;     // [0, 49152)
    if (j < 16384) {
      int kk = j & 127, n = j >> 7;
      Tai[n * 256 + 128 + kk] = f2bf(Wai[(size_t)(128 + kk) * 128 + n]);
    } else if (j < 32768) {
      int q = j - 16384;
      int kk = q & 127, n = q >> 7;
      Tah[n * 256 + 128 + kk] = f2bf(Wah[(size_t)(128 + kk) * 128 + n]);
    } else {
      int q = j - 32768;
      int k = q & 127, n = q >> 7;
      Tm1[n * 128 + k] = f2bf(Wm1[(size_t)k * 128 + n]);
    }
  } else {                            // ---- bvec ----
    int n = tid & 127;
    const float* bl = (tid < 128) ? bli : blh;
    const float* Wa = (tid < 128) ? Wai : Wah;
    float acc = 0.0f;
    for (int j = 0; j < 128; ++j) acc += bl[j] * Wa[j * 128 + n];
    if (tid < 128) bvi[n] = acc; else bvh[n] = acc;
  }
}

// ---------------------------------------------------------------------------
// CSR build. scatter hosts mw0 riders; fixed 4096-entry pk bins (0-based
// ccursor, memset init). R17: scatter also accumulates chist (hist merged).
// place computes CSR base via chist block reduction.
// ---------------------------------------------------------------------------
__global__ __launch_bounds__(256) void scatter_kernel(const int* __restrict__ ei,
                                                      const float* __restrict__ ew,
                                                      int* __restrict__ ccursor,
                                                      int* __restrict__ chist,
                                                      uint2* __restrict__ pk,
                                                      unsigned long long* __restrict__ mg0,
                                                      unsigned k00, unsigned k01) {
  if (blockIdx.x >= NTILES) {          // ---- mw0 rider blocks ----
    mask_chunk(mg0, (blockIdx.x - NTILES) * 256 + threadIdx.x, k00, k01);
    return;
  }
  __shared__ uint2 st[TILE];
  __shared__ unsigned short sbin[TILE];
  __shared__ int h[NBINS];
  __shared__ int base[NBINS];
  __shared__ int gbase[NBINS];
  __shared__ int cur[NBINS];
  __shared__ int sc[512];
  const int tid = threadIdx.x;
  const int e0 = blockIdx.x * TILE;
  const int nt = (N_EDGES - e0 < TILE) ? (N_EDGES - e0) : TILE;

  for (int i = tid; i < NBINS; i += 256) { h[i] = 0; cur[i] = 0; }
  __syncthreads();
  for (int j = tid; j < nt; j += 256) {
    int r = ei[e0 + j];
    r = (r < 0) ? 0 : (r >= N_NODES ? N_NODES - 1 : r);
    atomicAdd(&h[r >> 7], 1);
  }
  __syncthreads();
  sc[tid] = (tid < NBINS) ? h[tid] : 0;
  sc[tid + 256] = (tid + 256 < NBINS) ? h[tid + 256] : 0;
  __syncthreads();
  for (int off = 1; off < 512; off <<= 1) {
    int a0 = (tid >= off) ? sc[tid - off] : 0;
    int a1 = (tid + 256 >= off) ? sc[tid + 256 - off] : 0;
    __syncthreads();
    sc[tid] += a0; sc[tid + 256] += a1;
    __syncthreads();
  }
  if (tid < NBINS) {
    base[tid] = sc[tid] - h[tid];
    if (h[tid]) {
      gbase[tid] = tid * BSTR + atomicAdd(&ccursor[tid], h[tid]);
      atomicAdd(&chist[tid], h[tid]);           // hist merged (R17)
    }
  }
  if (tid + 256 < NBINS) {
    base[tid + 256] = sc[tid + 256] - h[tid + 256];
    if (h[tid + 256]) {
      gbase[tid + 256] = (tid + 256) * BSTR + atomicAdd(&ccursor[tid + 256], h[tid + 256]);
      atomicAdd(&chist[tid + 256], h[tid + 256]);
    }
  }
  __syncthreads();
  for (int j = tid; j < nt; j += 256) {
    int r = ei[e0 + j];
    r = (r < 0) ? 0 : (r >= N_NODES ? N_NODES - 1 : r);
    int c = ei[N_EDGES + e0 + j];
    c = (c < 0) ? 0 : (c >= N_NODES ? N_NODES - 1 : c);
    int bb = r >> 7;
    int slot = base[bb] + atomicAdd(&cur[bb], 1);
    uint2 p;
    p.x = ((unsigned)r << 16) | (unsigned)c;
    p.y = __float_as_uint(ew[e0 + j]);
    st[slot] = p;
    sbin[slot] = (unsigned short)bb;
  }
  __syncthreads();
  for (int j = tid; j < nt; j += 256) {
    int bb = sbin[j];
    pk[(size_t)gbase[bb] + (j - base[bb])] = st[j];
  }
}

__global__ __launch_bounds__(256) void place_kernel(const int* __restrict__ chist,
                                                    const uint2* __restrict__ pk,
                                                    uint2* __restrict__ csr,
                                                    int* __restrict__ rowptr,
                                                    float* __restrict__ invc) {
  __shared__ int red[256];
  __shared__ int lcnt[128];
  __shared__ int lpre[128];
  __shared__ int lcur[128];
  __shared__ int sc[128];
  const int b = blockIdx.x;
  const int tid = threadIdx.x;

  int psum = 0;
  for (int i = tid; i < b; i += 256) psum += chist[i];
  red[tid] = psum;
  __syncthreads();
  for (int off = 128; off > 0; off >>= 1) {
    if (tid < off) red[tid] += red[tid + off];
    __syncthreads();
  }
  const int cb = red[0];
  const int n = chist[b];
  const uint2* __restrict__ pkb = pk + (size_t)b * BSTR;
  const int r0 = b << 7;
  const int nr = (N_NODES - r0 < 128) ? (N_NODES - r0) : 128;

  if (tid < 128) { lcnt[tid] = 0; lcur[tid] = 0; }
  __syncthreads();
  for (int i = tid; i < n; i += 256) {
    int r7 = (int)(pkb[i].x >> 16) - r0;
    atomicAdd(&lcnt[r7], 1);
  }
  __syncthreads();
  if (tid < 128) sc[tid] = lcnt[tid];
  __syncthreads();
  for (int off = 1; off < 128; off <<= 1) {
    int tv = (tid >= off && tid < 128) ? sc[tid - off] : 0;
    __syncthreads();
    if (tid < 128) sc[tid] += tv;
    __syncthreads();
  }
  if (tid < 128) lpre[tid] = sc[tid] - lcnt[tid];
  __syncthreads();
  if (tid < nr) {
    rowptr[r0 + tid] = cb + lpre[tid];
    int c = lcnt[tid];
    invc[r0 + tid] = 1.0f / (float)(c > 1 ? c : 1);
  }
  if (b == NBINS - 1 && tid == 0) rowptr[N_NODES] = N_EDGES;
  for (int i = tid; i < n; i += 256) {
    uint2 p = pkb[i];
    int r7 = (int)(p.x >> 16) - r0;
    int slot = cb + lpre[r7] + atomicAdd(&lcur[r7], 1);
    uint2 o;
    o.x = p.x & 0xFFFFu;
    o.y = p.y;
    csr[slot] = o;
  }
}

// ---------------------------------------------------------------------------
// Aggregation (R12-verified core + R17 wave-uniform tail skip). One wave per
// row; CSR entries pre-loaded via ONE coalesced 8B/lane vector load; per-slot
// (col,w) from UNCONDITIONAL __shfl broadcasts (convergent — all 64 lanes
// active inside the wave-uniform group guard); ok-mask as VALU select.
// 4 edges wave-parallel x 16 dim-lanes. Emits sw when swout != null.
// ---------------------------------------------------------------------------
__global__ __launch_bounds__(256) void agg_kernel(const unsigned short* __restrict__ hlin,
                                                  const int* __restrict__ rowptr,
                                                  const uint2* __restrict__ csr,
                                                  const float* __restrict__ invc,
                                                  unsigned short* __restrict__ agg,
                                                  float* __restrict__ swout) {
  const int r = blockIdx.x * 4 + (threadIdx.x >> 6);
  const int lane = threadIdx.x & 63;
  const int es = lane >> 4;
  const int cg = lane & 15;
  const int start = rowptr[r];
  const int num = rowptr[r + 1] - start;
  const uint4* __restrict__ H = (const uint4*)hlin;   // 16 uint4 per row

  // vector preload of this row's CSR entries (clamped; safe when num==0)
  int qi = (num > 0) ? (start + (lane < num ? lane : num - 1)) : 0;
  uint2 myq = csr[qi];

  float a[8] = {0.f, 0.f, 0.f, 0.f, 0.f, 0.f, 0.f, 0.f};
  float ws = 0.f;
  const int nb = (num < 64) ? num : 64;
  for (int e = 0; e < nb; e += 16) {
#pragma unroll
    for (int j = 0; j < 4; ++j) {
      // wave-uniform group guard (e, j, nb uniform across the wave): skipped
      // groups only contributed w=0 terms — numerics identical, no shfl
      // convergence hazard (all 64 lanes take the same path).
      if (e + j * 4 < nb) {
        int idx = e + j * 4 + es;
        bool ok = idx < nb;
        int sl = ok ? idx : nb - 1;
        // UNCONDITIONAL convergent shfls (R11 post-mortem)
        int c0 = __shfl((int)myq.x, sl);
        int w0 = __shfl((int)myq.y, sl);
        unsigned col = (unsigned)c0;
        float w = ok ? __uint_as_float((unsigned)w0) : 0.0f;
        uint4 p = H[(size_t)col * 16 + cg];
        ws += w;
        a[0] += w * bflo(p.x); a[1] += w * bfhi(p.x);
        a[2] += w * bflo(p.y); a[3] += w * bfhi(p.y);
        a[4] += w * bflo(p.z); a[5] += w * bfhi(p.z);
        a[6] += w * bflo(p.w); a[7] += w * bfhi(p.w);
      }
    }
  }
  for (int e = 64; e < num; e += 16) {      // rare tail: degree > 64
#pragma unroll
    for (int j = 0; j < 4; ++j) {
      if (e + j * 4 < num) {
        int idx = e + j * 4 + es;
        bool ok = idx < num;
        int idxc = ok ? idx : (num - 1);
        uint2 q = csr[start + idxc];
        float w = ok ? __uint_as_float(q.y) : 0.0f;
        uint4 p = H[(size_t)q.x * 16 + cg];
        ws += w;
        a[0] += w * bflo(p.x); a[1] += w * bfhi(p.x);
        a[2] += w * bflo(p.y); a[3] += w * bfhi(p.y);
        a[4] += w * bflo(p.z); a[5] += w * bfhi(p.z);
        a[6] += w * bflo(p.w); a[7] += w * bfhi(p.w);
      }
    }
  }
#pragma unroll
  for (int k = 0; k < 8; ++k) {
    a[k] += __shfl_xor(a[k], 32);
    a[k] += __shfl_xor(a[k], 16);
  }
  ws += __shfl_xor(ws, 32);
  ws += __shfl_xor(ws, 16);
  const float s = invc[r];
  if (es == 0) {
    uint4 o;
    o.x = (unsigned)f2bf(a[0] * s) | ((unsigned)f2bf(a[1] * s) << 16);
    o.y = (unsigned)f2bf(a[2] * s) | ((unsigned)f2bf(a[3] * s) << 16);
    o.z = (unsigned)f2bf(a[4] * s) | ((unsigned)f2bf(a[5] * s) << 16);
    o.w = (unsigned)f2bf(a[6] * s) | ((unsigned)f2bf(a[7] * s) << 16);
    ((uint4*)agg)[(size_t)r * 16 + cg] = o;
  }
  if (swout && lane == 0) swout[r] = ws * s;
}

// ---------------------------------------------------------------------------
// Layer GEMM (R15-verified): 512 threads, 128 rows x 128 cols per block,
// 8 waves (4 wm x 2 wn), per-wave 32x64 tile = 2x4 MFMA 16x16x32, K=256 over
// [Agg | Hin] @ Wt. LDS 36.9KB -> 4 blk/CU = 32 waves/CU.
// Epilogue: +sw*bvec+bagg, ReLU, bit-packed dropout, bf16 store (+fp32 when
// WF32). MASKGEN: blocks >= GB128 generate one threefry mask stream.
// MLP (layer 3): h-tile to LDS tT, t = relu(h @ Tm1 + b1) via MFMA, then
// y = t @ W2 + b2 via MFMA (W2 pre-staged as bf16 [16][132] in LDS).
// ---------------------------------------------------------------------------
template <bool WF32, bool MASKGEN, bool MLP>
__global__ __launch_bounds__(512) void layer_gemm(
    const unsigned short* __restrict__ Agg, const unsigned short* __restrict__ Hin,
    const unsigned short* __restrict__ Wt,   // [128 cols][256 k] bf16
    const float* __restrict__ bvec, const float* __restrict__ bagg,
    const float* __restrict__ sw,
    const unsigned long long* __restrict__ maskw,
    float* __restrict__ outf, unsigned short* __restrict__ outb,
    unsigned long long* __restrict__ gm, unsigned gk0, unsigned gk1,
    const unsigned short* __restrict__ Wt2,  // Tm1 [128 cols][128 k] (MLP)
    const float* __restrict__ b1,
    const float* __restrict__ W2, const float* __restrict__ b2,
    float* __restrict__ y) {
  if (MASKGEN && blockIdx.x >= GB128) {
    mask_chunk(gm, (blockIdx.x - GB128) * 512 + threadIdx.x, gk0, gk1);
    return;
  }
  constexpr int LS = 72;
  constexpr int LT = 132;
  __shared__ unsigned short Als[128 * LS];   // 18.4 KB
  __shared__ unsigned short Bls[128 * LS];   // 18.4 KB
  __shared__ unsigned short tT[MLP ? 128 * LT : 2];   // 33.8 KB (MLP only)
  __shared__ unsigned short Wsb[MLP ? 16 * LT : 2];   // 4.2 KB  (MLP only)
  __shared__ float bs[MLP ? DOUT : 1];
  const int tid = threadIdx.x;
  const int m0 = blockIdx.x * 128;
  const int lane = tid & 63;
  const int wid = tid >> 6;                 // 0..7
  const int wm = (wid >> 1) * 32;           // 0,32,64,96
  const int wn = (wid & 1) * 64;            // 0,64
  const int ln = lane & 15;
  const int lh = lane >> 4;
  const int sArow = tid >> 2;               // 0..127
  const int sAk = (tid & 3) * 16;
  int arow = m0 + sArow;
  if (arow >= N_NODES) arow = N_NODES - 1;

  if (MLP) {
    // stage W2 -> bf16 [16 cols][LT k] (cols >= DOUT zero) + b2
    for (int i = tid; i < 16 * 128; i += 512) {
      int c = i >> 7, k = i & 127;
      Wsb[c * LT + k] = (c < DOUT) ? f2bf(W2[(size_t)k * DOUT + c]) : (unsigned short)0;
    }
    if (tid < DOUT) bs[tid] = b2[tid];
  }

  f32x4 acc[2][4];
#pragma unroll
  for (int i = 0; i < 2; ++i)
#pragma unroll
    for (int j = 0; j < 4; ++j)
#pragma unroll
      for (int r = 0; r < 4; ++r) acc[i][j][r] = 0.0f;

  for (int kb = 0; kb < 256; kb += 64) {
    const unsigned short* Asrc = (kb < 128) ? Agg : Hin;
    const unsigned short* ap = Asrc + (size_t)arow * 128 + (kb & 127) + sAk;
    unsigned short* al = &Als[sArow * LS + sAk];
    *(uint4*)(al + 0) = *(const uint4*)(ap + 0);
    *(uint4*)(al + 8) = *(const uint4*)(ap + 8);
    const unsigned short* bp = Wt + (size_t)sArow * 256 + kb + sAk;  // sArow = col here
    unsigned short* bl = &Bls[sArow * LS + sAk];
    *(uint4*)(bl + 0) = *(const uint4*)(bp + 0);
    *(uint4*)(bl + 8) = *(const uint4*)(bp + 8);
    __syncthreads();
#pragma unroll
    for (int ks = 0; ks < 64; ks += 32) {
      bf16x8 af[2], bfr[4];
#pragma unroll
      for (int i = 0; i < 2; ++i)
        af[i] = *(const bf16x8*)&Als[(wm + i * 16 + ln) * LS + ks + lh * 8];
#pragma unroll
      for (int j = 0; j < 4; ++j)
        bfr[j] = *(const bf16x8*)&Bls[(wn + j * 16 + ln) * LS + ks + lh * 8];
#pragma unroll
      for (int i = 0; i < 2; ++i)
#pragma unroll
        for (int j = 0; j < 4; ++j)
          acc[i][j] = __builtin_amdgcn_mfma_f32_16x16x32_bf16(af[i], bfr[j], acc[i][j], 0, 0, 0);
    }
    __syncthreads();
  }

  // epilogue: C/D map col=lane&15, row=(lane>>4)*4+reg  [m89/m91]
  const int lm = lane >> 4;
  float bc[4], b2c[4];
#pragma unroll
  for (int j = 0; j < 4; ++j) {
    int col = wn + j * 16 + ln;
    bc[j] = bvec[col];
    b2c[j] = bagg[col];
  }
#pragma unroll
  for (int i = 0; i < 2; ++i) {
    const int lr0 = wm + i * 16 + lm * 4;
#pragma unroll
    for (int r = 0; r < 4; ++r) {
      const int row = m0 + lr0 + r;
      if (row >= N_NODES) continue;
      const float swr = sw[row];
      const unsigned long long mw = maskw[(size_t)row * 2 + (wn >> 6)];
#pragma unroll
      for (int j = 0; j < 4; ++j) {
        const int col = wn + j * 16 + ln;
        float v = acc[i][j][r] + swr * bc[j] + b2c[j];
        v = fmaxf(v, 0.0f);
        v = ((mw >> (col & 63)) & 1ull) ? 2.0f * v : 0.0f;
        if (WF32) outf[(size_t)row * DGN + col] = v;
        if (MLP) tT[(lr0 + r) * LT + col] = f2bf(v);
        else outb[(size_t)row * DGN + col] = f2bf(v);
      }
    }
  }

  if (MLP) {
    __syncthreads();   // tT complete; Bls free for Tm1

    f32x4 acc2[2][4];
#pragma unroll
    for (int i = 0; i < 2; ++i)
#pragma unroll
      for (int j = 0; j < 4; ++j)
#pragma unroll
        for (int r = 0; r < 4; ++r) acc2[i][j][r] = 0.0f;

    for (int kb = 0; kb < 128; kb += 64) {
      const unsigned short* bp = Wt2 + (size_t)sArow * 128 + kb + sAk;
      unsigned short* bl = &Bls[sArow * LS + sAk];
      *(uint4*)(bl + 0) = *(const uint4*)(bp + 0);
      *(uint4*)(bl + 8) = *(const uint4*)(bp + 8);
      __syncthreads();
#pragma unroll
      for (int ks = 0; ks < 64; ks += 32) {
        bf16x8 af[2], bfr[4];
#pragma unroll
        for (int i = 0; i < 2; ++i)
          af[i] = *(const bf16x8*)&tT[(wm + i * 16 + ln) * LT + kb + ks + lh * 8];
#pragma unroll
        for (int j = 0; j < 4; ++j)
          bfr[j] = *(const bf16x8*)&Bls[(wn + j * 16 + ln) * LS + ks + lh * 8];
#pragma unroll
        for (int i = 0; i < 2; ++i)
#pragma unroll
          for (int j = 0; j < 4; ++j)
            acc2[i][j] = __builtin_amdgcn_mfma_f32_16x16x32_bf16(af[i], bfr[j], acc2[i][j], 0, 0, 0);
      }
      __syncthreads();
    }

    // epilogue2 -> t tile (overwrites tT; all A reads done)
    float bcol[4];
#pragma unroll
    for (int j = 0; j < 4; ++j) bcol[j] = b1[wn + j * 16 + ln];
#pragma unroll
    for (int i = 0; i < 2; ++i) {
      const int lr0 = wm + i * 16 + lm * 4;
#pragma unroll
      for (int r = 0; r < 4; ++r) {
        const int lr = lr0 + r;
#pragma unroll
        for (int j = 0; j < 4; ++j) {
          const int col = wn + j * 16 + ln;
          float v = fmaxf(acc2[i][j][r] + bcol[j], 0.0f);
          tT[lr * LT + col] = f2bf(v);
        }
      }
    }
    __syncthreads();

    // mlp2 via MFMA: wave w handles rows w*16..w*16+15, cols 0..15 (10 used)
    f32x4 acc3;
#pragma unroll
    for (int r = 0; r < 4; ++r) acc3[r] = 0.0f;
#pragma unroll
    for (int kt = 0; kt < 4; ++kt) {
      bf16x8 af = *(const bf16x8*)&tT[(wid * 16 + ln) * LT + kt * 32 + lh * 8];
      bf16x8 bw = *(const bf16x8*)&Wsb[ln * LT + kt * 32 + lh * 8];
      acc3 = __builtin_amdgcn_mfma_f32_16x16x32_bf16(af, bw, acc3, 0, 0, 0);
    }
    if (ln < DOUT) {
#pragma unroll
      for (int r = 0; r < 4; ++r) {
        const int row = m0 + wid * 16 + lm * 4 + r;
        if (row < N_NODES) y[(size_t)row * DOUT + ln] = acc3[r] + bs[ln];
      }
    }
  }
}

// ---------------------------------------------------------------------------
extern "C" void kernel_launch(void* const* d_in, const int* in_sizes, int n_in,
                              void* d_out, int out_size, void* d_ws, size_t ws_size,
                              hipStream_t stream) {
  const float* x        = (const float*)d_in[0];
  const int*   ei       = (const int*)d_in[1];
  const float* ew       = (const float*)d_in[2];
  const float* W_lin_in = (const float*)d_in[3];
  const float* b_lin_in = (const float*)d_in[4];
  const float* W_agg_in = (const float*)d_in[5];
  const float* b_agg_in = (const float*)d_in[6];
  const float* W_lin_h  = (const float*)d_in[7];
  const float* b_lin_h  = (const float*)d_in[8];
  const float* W_agg_h  = (const float*)d_in[9];
  const float* b_agg_h  = (const float*)d_in[10];
  const float* W_mlp1   = (const float*)d_in[11];
  const float* b_mlp1   = (const float*)d_in[12];
  const float* W_mlp2   = (const float*)d_in[13];
  const float* b_mlp2   = (const float*)d_in[14];

  float* hout = (float*)d_out;
  float* yout = hout + (size_t)NELEM;

  char* p = (char*)d_ws;
  auto alloc = [&](size_t bytes) {
    char* q = p;
    p += (bytes + 255) & ~(size_t)255;
    return q;
  };
  int*   chist   = (int*)alloc((size_t)(NBINS + 1) * 4);
  int*   ccursor = (int*)alloc((size_t)NBINS * 4);
  int*   rowptr  = (int*)alloc((size_t)(N_NODES + 1) * 4);
  float* invc    = (float*)alloc((size_t)N_NODES * 4);
  float* swv     = (float*)alloc((size_t)N_NODES * 4);
  uint2* pk      = (uint2*)alloc((size_t)NBINS * BSTR * 8);
  uint2* csr     = (uint2*)alloc((size_t)N_EDGES * 8);
  unsigned short* xb   = (unsigned short*)alloc((size_t)NELEM * 2);
  unsigned short* aggb = (unsigned short*)alloc((size_t)NELEM * 2);
  unsigned short* hA   = (unsigned short*)alloc((size_t)NELEM * 2);
  unsigned short* hB   = (unsigned short*)alloc((size_t)NELEM * 2);
  unsigned long long* mw0 = (unsigned long long*)alloc((size_t)NMASKW * 8);
  unsigned long long* mw1 = (unsigned long long*)alloc((size_t)NMASKW * 8);
  unsigned long long* mw2 = (unsigned long long*)alloc((size_t)NMASKW * 8);
  unsigned short* Tai = (unsigned short*)alloc(32768 * 2);
  unsigned short* Tah = (unsigned short*)alloc(32768 * 2);
  unsigned short* Tm1 = (unsigned short*)alloc(16384 * 2);
  float* bvi = (float*)alloc(128 * 4);
  float* bvh = (float*)alloc(128 * 4);

  unsigned dk[3][2];
  for (unsigned i = 0; i < 3; ++i) tf2x32(0u, 42u, 0u, i, dk[i][0], dk[i][1]);

  // ---- prep ----
  hipMemsetAsync(chist, 0, (size_t)(NBINS + 1) * 4, stream);
  hipMemsetAsync(ccursor, 0, (size_t)NBINS * 4, stream);
  mega_kernel<<<MEGA_BLOCKS, 256, 0, stream>>>(
      x, xb, W_lin_in, W_agg_in, W_lin_h, W_agg_h, W_mlp1,
      b_lin_in, b_lin_h, Tai, Tah, Tm1, bvi, bvh);

  // ---- CSR build (+ mw0 riders on scatter; hist merged into scatter) ----
  scatter_kernel<<<NTILES + MK_BLOCKS, 256, 0, stream>>>(
      ei, ew, ccursor, chist, pk, mw0, dk[0][0], dk[0][1]);
  place_kernel<<<NBINS, 256, 0, stream>>>(chist, pk, csr, rowptr, invc);

  // ---- layer 1 (+ mw1 riders on gemm1) ----
  agg_kernel<<<AB_BLOCKS, 256, 0, stream>>>(xb, rowptr, csr, invc, aggb, swv);
  layer_gemm<false, true, false><<<GB128 + MKB512, 512, 0, stream>>>(
      aggb, xb, Tai, bvi, b_agg_in, swv, mw0, nullptr, hA,
      mw1, dk[1][0], dk[1][1], nullptr, nullptr, nullptr, nullptr, nullptr);

  // ---- layer 2 (+ mw2 riders on gemm2) ----
  agg_kernel<<<AB_BLOCKS, 256, 0, stream>>>(hA, rowptr, csr, invc, aggb, nullptr);
  layer_gemm<false, true, false><<<GB128 + MKB512, 512, 0, stream>>>(
      aggb, hA, Tah, bvh, b_agg_h, swv, mw1, nullptr, hB,
      mw2, dk[2][0], dk[2][1], nullptr, nullptr, nullptr, nullptr, nullptr);

  // ---- layer 3 (mlp fused into gemm3, MFMA mlp2) ----
  agg_kernel<<<AB_BLOCKS, 256, 0, stream>>>(hB, rowptr, csr, invc, aggb, nullptr);
  layer_gemm<true, false, true><<<GB128, 512, 0, stream>>>(
      aggb, hB, Tah, bvh, b_agg_h, swv, mw2, hout, nullptr,
      nullptr, 0, 0, Tm1, b_mlp1, W_mlp2, b_mlp2, yout);
}

// Round 9
// 290.916 us; speedup vs baseline: 1.0705x; 1.0437x over previous
//
#include <hip/hip_runtime.h>
#include <cstdint>
#include <cstddef>

// ---------------------------------------------------------------------------
// ReweightGNN: 3x GraphSAGE-reweight (lmda=1.0) + dropout(0.5) + 2-layer MLP
// N=50000, E=800000, D=128, DOUT=10. Outputs: h [N,128] fp32, y [N,10] fp32.
// R18 = R15 agg core restored (R17's wave-uniform tail skip REVERTED — the
// per-group branch fragmented the 4-load batch into load->wait->FMA blocks,
// serializing gather latency; straight-line waste is cheaper than lost MLP)
// + kept from R17: hist merged into scatter, mega hist blocks removed.
// ---------------------------------------------------------------------------

#define N_NODES 50000
#define N_EDGES 800000
#define DGN 128
#define DOUT 10
#define NELEM (N_NODES * DGN)       // 6,400,000
#define NMASKW (NELEM / 64)         // 100,000 uint64 words per mask
#define NBINS 391                   // ceil(50000/128) coarse bins (row>>7)
#define TILE 4096                   // edges per scatter block
#define BSTR 4096                   // pk entries reserved per bin
#define NTILES ((N_EDGES + TILE - 1) / TILE)   // 196
#define GB128 ((N_NODES + 127) / 128)   // 391 gemm blocks (128 rows x 128 cols)
#define MK_BLOCKS 25000             // 256-thread rider blocks (scatter host)
#define MKB512 12500                // 512-thread rider blocks (gemm hosts)

// mega-kernel block ranges (hist removed — lives in scatter now)
#define XB_BLK 6250                 // x fp32->bf16 (1.6M float4)
#define WC_BLK 128
#define TR_BLK 192
#define R0 XB_BLK
#define R1 (R0 + WC_BLK)
#define R2 (R1 + TR_BLK)
#define MEGA_BLOCKS (R2 + 1)

#define AB_BLOCKS ((N_NODES + 3) / 4)   // 12500 agg blocks (4 rows each)

typedef __attribute__((ext_vector_type(8))) short bf16x8;
typedef __attribute__((ext_vector_type(4))) float f32x4;

__host__ __device__ static inline unsigned short f2bf(float f) {
  union { float f; unsigned u; } c; c.f = f;
  unsigned u = c.u;
  return (unsigned short)((u + 0x7fffu + ((u >> 16) & 1u)) >> 16);  // RNE
}
__device__ static inline float bflo(unsigned u) { return __uint_as_float(u << 16); }
__device__ static inline float bfhi(unsigned u) { return __uint_as_float(u & 0xffff0000u); }

// ---------------------------------------------------------------------------
// threefry2x32 (exact JAX)
// ---------------------------------------------------------------------------
__host__ __device__ static inline void tf2x32(unsigned k0, unsigned k1,
                                              unsigned c0, unsigned c1,
                                              unsigned& o0, unsigned& o1) {
  unsigned ks2 = k0 ^ k1 ^ 0x1BD11BDAu;
  unsigned x0 = c0 + k0;
  unsigned x1 = c1 + k1;
#define TFR(r) { x0 += x1; x1 = (x1 << (r)) | (x1 >> (32 - (r))); x1 ^= x0; }
  TFR(13) TFR(15) TFR(26) TFR(6)
  x0 += k1;  x1 += ks2 + 1u;
  TFR(17) TFR(29) TFR(16) TFR(24)
  x0 += ks2; x1 += k0 + 2u;
  TFR(13) TFR(15) TFR(26) TFR(6)
  x0 += k0;  x1 += k1 + 3u;
  TFR(17) TFR(29) TFR(16) TFR(24)
  x0 += k1;  x1 += ks2 + 4u;
  TFR(13) TFR(15) TFR(26) TFR(6)
  x0 += ks2; x1 += k0 + 5u;
#undef TFR
  o0 = x0; o1 = x1;
}

// one bit-packed mask stream chunk (rider blocks use this)
__device__ static inline void mask_chunk(unsigned long long* __restrict__ gm,
                                         int i, unsigned k0, unsigned k1) {
  unsigned o0, o1;
  tf2x32(k0, k1, 0u, (unsigned)i, o0, o1);
  unsigned long long b = __ballot(((o0 ^ o1) >> 31) == 0u);
  if ((threadIdx.x & 63) == 0) gm[i >> 6] = b;
}

// ---------------------------------------------------------------------------
// Mega prep kernel: x convert | W_comb | transposes | bvec
// ---------------------------------------------------------------------------
__global__ __launch_bounds__(256) void mega_kernel(
    const float* __restrict__ x, unsigned short* __restrict__ xb,
    const float* __restrict__ Wli, const float* __restrict__ Wai,
    const float* __restrict__ Wlh, const float* __restrict__ Wah,
    const float* __restrict__ Wm1,
    const float* __restrict__ bli, const float* __restrict__ blh,
    unsigned short* __restrict__ Tai, unsigned short* __restrict__ Tah,
    unsigned short* __restrict__ Tm1,
    float* __restrict__ bvi, float* __restrict__ bvh) {
  const int b = blockIdx.x;
  const int tid = threadIdx.x;

  if (b < R0) {                       // ---- x convert ----
    int g = b * 256 + tid;
    float4 v = ((const float4*)x)[g];
    ushort4 o;
    o.x = f2bf(v.x); o.y = f2bf(v.y); o.z = f2bf(v.z); o.w = f2bf(v.w);
    ((ushort4*)xb)[g] = o;
  } else if (b < R1) {                // ---- W_comb (fp32 accumulate) ----
    int idx = (b - R0) * 256 + tid;   // [0, 32768)
    int n = idx & 127;
    int k = (idx >> 7) & 127;
    int m = idx >> 14;                // 0: in-layer, 1: hidden
    const float* Wl = m ? Wlh : Wli;
    const float* Wa = m ? Wah : Wai;
    unsigned short* T = m ? Tah : Tai;
    float acc = 0.0f;
#pragma unroll 8
    for (int j = 0; j < 128; ++j)
      acc += Wl[k * 128 + j] * Wa[j * 128 + n];
    T[n * 256 + k] = f2bf(acc);
  } else if (b < R2) {                // ---- transposes ----
    int j = (b - R1) * 256 + tid;     // [0, 49152)
    if (j < 16384) {
      int kk = j & 127, n = j >> 7;
      Tai[n * 256 + 128 + kk] = f2bf(Wai[(size_t)(128 + kk) * 128 + n]);
    } else if (j < 32768) {
      int q = j - 16384;
      int kk = q & 127, n = q >> 7;
      Tah[n * 256 + 128 + kk] = f2bf(Wah[(size_t)(128 + kk) * 128 + n]);
    } else {
      int q = j - 32768;
      int k = q & 127, n = q >> 7;
      Tm1[n * 128 + k] = f2bf(Wm1[(size_t)k * 128 + n]);
    }
  } else {                            // ---- bvec ----
    int n = tid & 127;
    const float* bl = (tid < 128) ? bli : blh;
    const float* Wa = (tid < 128) ? Wai : Wah;
    float acc = 0.0f;
    for (int j = 0; j < 128; ++j) acc += bl[j] * Wa[j * 128 + n];
    if (tid < 128) bvi[n] = acc; else bvh[n] = acc;
  }
}

// ---------------------------------------------------------------------------
// CSR build. scatter hosts mw0 riders; fixed 4096-entry pk bins (0-based
// ccursor, memset init); scatter also accumulates chist (hist merged, R17).
// place computes CSR base via chist block reduction.
// ---------------------------------------------------------------------------
__global__ __launch_bounds__(256) void scatter_kernel(const int* __restrict__ ei,
                                                      const float* __restrict__ ew,
                                                      int* __restrict__ ccursor,
                                                      int* __restrict__ chist,
                                                      uint2* __restrict__ pk,
                                                      unsigned long long* __restrict__ mg0,
                                                      unsigned k00, unsigned k01) {
  if (blockIdx.x >= NTILES) {          // ---- mw0 rider blocks ----
    mask_chunk(mg0, (blockIdx.x - NTILES) * 256 + threadIdx.x, k00, k01);
    return;
  }
  __shared__ uint2 st[TILE];
  __shared__ unsigned short sbin[TILE];
  __shared__ int h[NBINS];
  __shared__ int base[NBINS];
  __shared__ int gbase[NBINS];
  __shared__ int cur[NBINS];
  __shared__ int sc[512];
  const int tid = threadIdx.x;
  const int e0 = blockIdx.x * TILE;
  const int nt = (N_EDGES - e0 < TILE) ? (N_EDGES - e0) : TILE;

  for (int i = tid; i < NBINS; i += 256) { h[i] = 0; cur[i] = 0; }
  __syncthreads();
  for (int j = tid; j < nt; j += 256) {
    int r = ei[e0 + j];
    r = (r < 0) ? 0 : (r >= N_NODES ? N_NODES - 1 : r);
    atomicAdd(&h[r >> 7], 1);
  }
  __syncthreads();
  sc[tid] = (tid < NBINS) ? h[tid] : 0;
  sc[tid + 256] = (tid + 256 < NBINS) ? h[tid + 256] : 0;
  __syncthreads();
  for (int off = 1; off < 512; off <<= 1) {
    int a0 = (tid >= off) ? sc[tid - off] : 0;
    int a1 = (tid + 256 >= off) ? sc[tid + 256 - off] : 0;
    __syncthreads();
    sc[tid] += a0; sc[tid + 256] += a1;
    __syncthreads();
  }
  if (tid < NBINS) {
    base[tid] = sc[tid] - h[tid];
    if (h[tid]) {
      gbase[tid] = tid * BSTR + atomicAdd(&ccursor[tid], h[tid]);
      atomicAdd(&chist[tid], h[tid]);           // hist merged (R17)
    }
  }
  if (tid + 256 < NBINS) {
    base[tid + 256] = sc[tid + 256] - h[tid + 256];
    if (h[tid + 256]) {
      gbase[tid + 256] = (tid + 256) * BSTR + atomicAdd(&ccursor[tid + 256], h[tid + 256]);
      atomicAdd(&chist[tid + 256], h[tid + 256]);
    }
  }
  __syncthreads();
  for (int j = tid; j < nt; j += 256) {
    int r = ei[e0 + j];
    r = (r < 0) ? 0 : (r >= N_NODES ? N_NODES - 1 : r);
    int c = ei[N_EDGES + e0 + j];
    c = (c < 0) ? 0 : (c >= N_NODES ? N_NODES - 1 : c);
    int bb = r >> 7;
    int slot = base[bb] + atomicAdd(&cur[bb], 1);
    uint2 p;
    p.x = ((unsigned)r << 16) | (unsigned)c;
    p.y = __float_as_uint(ew[e0 + j]);
    st[slot] = p;
    sbin[slot] = (unsigned short)bb;
  }
  __syncthreads();
  for (int j = tid; j < nt; j += 256) {
    int bb = sbin[j];
    pk[(size_t)gbase[bb] + (j - base[bb])] = st[j];
  }
}

__global__ __launch_bounds__(256) void place_kernel(const int* __restrict__ chist,
                                                    const uint2* __restrict__ pk,
                                                    uint2* __restrict__ csr,
                                                    int* __restrict__ rowptr,
                                                    float* __restrict__ invc) {
  __shared__ int red[256];
  __shared__ int lcnt[128];
  __shared__ int lpre[128];
  __shared__ int lcur[128];
  __shared__ int sc[128];
  const int b = blockIdx.x;
  const int tid = threadIdx.x;

  int psum = 0;
  for (int i = tid; i < b; i += 256) psum += chist[i];
  red[tid] = psum;
  __syncthreads();
  for (int off = 128; off > 0; off >>= 1) {
    if (tid < off) red[tid] += red[tid + off];
    __syncthreads();
  }
  const int cb = red[0];
  const int n = chist[b];
  const uint2* __restrict__ pkb = pk + (size_t)b * BSTR;
  const int r0 = b << 7;
  const int nr = (N_NODES - r0 < 128) ? (N_NODES - r0) : 128;

  if (tid < 128) { lcnt[tid] = 0; lcur[tid] = 0; }
  __syncthreads();
  for (int i = tid; i < n; i += 256) {
    int r7 = (int)(pkb[i].x >> 16) - r0;
    atomicAdd(&lcnt[r7], 1);
  }
  __syncthreads();
  if (tid < 128) sc[tid] = lcnt[tid];
  __syncthreads();
  for (int off = 1; off < 128; off <<= 1) {
    int tv = (tid >= off && tid < 128) ? sc[tid - off] : 0;
    __syncthreads();
    if (tid < 128) sc[tid] += tv;
    __syncthreads();
  }
  if (tid < 128) lpre[tid] = sc[tid] - lcnt[tid];
  __syncthreads();
  if (tid < nr) {
    rowptr[r0 + tid] = cb + lpre[tid];
    int c = lcnt[tid];
    invc[r0 + tid] = 1.0f / (float)(c > 1 ? c : 1);
  }
  if (b == NBINS - 1 && tid == 0) rowptr[N_NODES] = N_EDGES;
  for (int i = tid; i < n; i += 256) {
    uint2 p = pkb[i];
    int r7 = (int)(p.x >> 16) - r0;
    int slot = cb + lpre[r7] + atomicAdd(&lcur[r7], 1);
    uint2 o;
    o.x = p.x & 0xFFFFu;
    o.y = p.y;
    csr[slot] = o;
  }
}

// ---------------------------------------------------------------------------
// Aggregation (R12/R15-verified core, straight-line unroll — NO per-group
// branches: the 4 gathers must issue as one batch for latency hiding; clamped
// slots contribute w=0, numerics identical). One wave per row; CSR entries
// pre-loaded via ONE coalesced 8B/lane vector load; per-slot (col,w) from
// UNCONDITIONAL __shfl broadcasts (convergent); ok-mask as VALU select.
// 4 edges wave-parallel x 16 dim-lanes. Emits sw when swout != null.
// ---------------------------------------------------------------------------
__global__ __launch_bounds__(256) void agg_kernel(const unsigned short* __restrict__ hlin,
                                                  const int* __restrict__ rowptr,
                                                  const uint2* __restrict__ csr,
                                                  const float* __restrict__ invc,
                                                  unsigned short* __restrict__ agg,
                                                  float* __restrict__ swout) {
  const int r = blockIdx.x * 4 + (threadIdx.x >> 6);
  const int lane = threadIdx.x & 63;
  const int es = lane >> 4;
  const int cg = lane & 15;
  const int start = rowptr[r];
  const int num = rowptr[r + 1] - start;
  const uint4* __restrict__ H = (const uint4*)hlin;   // 16 uint4 per row

  // vector preload of this row's CSR entries (clamped; safe when num==0)
  int qi = (num > 0) ? (start + (lane < num ? lane : num - 1)) : 0;
  uint2 myq = csr[qi];

  float a[8] = {0.f, 0.f, 0.f, 0.f, 0.f, 0.f, 0.f, 0.f};
  float ws = 0.f;
  const int nb = (num < 64) ? num : 64;
  for (int e = 0; e < nb; e += 16) {
#pragma unroll
    for (int j = 0; j < 4; ++j) {
      int idx = e + j * 4 + es;
      bool ok = idx < nb;
      int sl = ok ? idx : nb - 1;
      // UNCONDITIONAL convergent shfls (R11 post-mortem): plain statements so
      // no lane is exec-masked out of the bpermute.
      int c0 = __shfl((int)myq.x, sl);
      int w0 = __shfl((int)myq.y, sl);
      unsigned col = (unsigned)c0;
      float w = ok ? __uint_as_float((unsigned)w0) : 0.0f;
      uint4 p = H[(size_t)col * 16 + cg];
      ws += w;
      a[0] += w * bflo(p.x); a[1] += w * bfhi(p.x);
      a[2] += w * bflo(p.y); a[3] += w * bfhi(p.y);
      a[4] += w * bflo(p.z); a[5] += w * bfhi(p.z);
      a[6] += w * bflo(p.w); a[7] += w * bfhi(p.w);
    }
  }
  for (int e = 64; e < num; e += 16) {      // rare tail: degree > 64
#pragma unroll
    for (int j = 0; j < 4; ++j) {
      int idx = e + j * 4 + es;
      bool ok = idx < num;
      int idxc = ok ? idx : (num - 1);
      uint2 q = csr[start + idxc];
      float w = ok ? __uint_as_float(q.y) : 0.0f;
      uint4 p = H[(size_t)q.x * 16 + cg];
      ws += w;
      a[0] += w * bflo(p.x); a[1] += w * bfhi(p.x);
      a[2] += w * bflo(p.y); a[3] += w * bfhi(p.y);
      a[4] += w * bflo(p.z); a[5] += w * bfhi(p.z);
      a[6] += w * bflo(p.w); a[7] += w * bfhi(p.w);
    }
  }
#pragma unroll
  for (int k = 0; k < 8; ++k) {
    a[k] += __shfl_xor(a[k], 32);
    a[k] += __shfl_xor(a[k], 16);
  }
  ws += __shfl_xor(ws, 32);
  ws += __shfl_xor(ws, 16);
  const float s = invc[r];
  if (es == 0) {
    uint4 o;
    o.x = (unsigned)f2bf(a[0] * s) | ((unsigned)f2bf(a[1] * s) << 16);
    o.y = (unsigned)f2bf(a[2] * s) | ((unsigned)f2bf(a[3] * s) << 16);
    o.z = (unsigned)f2bf(a[4] * s) | ((unsigned)f2bf(a[5] * s) << 16);
    o.w = (unsigned)f2bf(a[6] * s) | ((unsigned)f2bf(a[7] * s) << 16);
    ((uint4*)agg)[(size_t)r * 16 + cg] = o;
  }
  if (swout && lane == 0) swout[r] = ws * s;
}

// ---------------------------------------------------------------------------
// Layer GEMM (R15-verified): 512 threads, 128 rows x 128 cols per block,
// 8 waves (4 wm x 2 wn), per-wave 32x64 tile = 2x4 MFMA 16x16x32, K=256 over
// [Agg | Hin] @ Wt. LDS 36.9KB -> 4 blk/CU = 32 waves/CU.
// Epilogue: +sw*bvec+bagg, ReLU, bit-packed dropout, bf16 store (+fp32 when
// WF32). MASKGEN: blocks >= GB128 generate one threefry mask stream.
// MLP (layer 3): h-tile to LDS tT, t = relu(h @ Tm1 + b1) via MFMA, then
// y = t @ W2 + b2 via MFMA (W2 pre-staged as bf16 [16][132] in LDS).
// ---------------------------------------------------------------------------
template <bool WF32, bool MASKGEN, bool MLP>
__global__ __launch_bounds__(512) void layer_gemm(
    const unsigned short* __restrict__ Agg, const unsigned short* __restrict__ Hin,
    const unsigned short* __restrict__ Wt,   // [128 cols][256 k] bf16
    const float* __restrict__ bvec, const float* __restrict__ bagg,
    const float* __restrict__ sw,
    const unsigned long long* __restrict__ maskw,
    float* __restrict__ outf, unsigned short* __restrict__ outb,
    unsigned long long* __restrict__ gm, unsigned gk0, unsigned gk1,
    const unsigned short* __restrict__ Wt2,  // Tm1 [128 cols][128 k] (MLP)
    const float* __restrict__ b1,
    const float* __restrict__ W2, const float* __restrict__ b2,
    float* __restrict__ y) {
  if (MASKGEN && blockIdx.x >= GB128) {
    mask_chunk(gm, (blockIdx.x - GB128) * 512 + threadIdx.x, gk0, gk1);
    return;
  }
  constexpr int LS = 72;
  constexpr int LT = 132;
  __shared__ unsigned short Als[128 * LS];   // 18.4 KB
  __shared__ unsigned short Bls[128 * LS];   // 18.4 KB
  __shared__ unsigned short tT[MLP ? 128 * LT : 2];   // 33.8 KB (MLP only)
  __shared__ unsigned short Wsb[MLP ? 16 * LT : 2];   // 4.2 KB  (MLP only)
  __shared__ float bs[MLP ? DOUT : 1];
  const int tid = threadIdx.x;
  const int m0 = blockIdx.x * 128;
  const int lane = tid & 63;
  const int wid = tid >> 6;                 // 0..7
  const int wm = (wid >> 1) * 32;           // 0,32,64,96
  const int wn = (wid & 1) * 64;            // 0,64
  const int ln = lane & 15;
  const int lh = lane >> 4;
  const int sArow = tid >> 2;               // 0..127
  const int sAk = (tid & 3) * 16;
  int arow = m0 + sArow;
  if (arow >= N_NODES) arow = N_NODES - 1;

  if (MLP) {
    // stage W2 -> bf16 [16 cols][LT k] (cols >= DOUT zero) + b2
    for (int i = tid; i < 16 * 128; i += 512) {
      int c = i >> 7, k = i & 127;
      Wsb[c * LT + k] = (c < DOUT) ? f2bf(W2[(size_t)k * DOUT + c]) : (unsigned short)0;
    }
    if (tid < DOUT) bs[tid] = b2[tid];
  }

  f32x4 acc[2][4];
#pragma unroll
  for (int i = 0; i < 2; ++i)
#pragma unroll
    for (int j = 0; j < 4; ++j)
#pragma unroll
      for (int r = 0; r < 4; ++r) acc[i][j][r] = 0.0f;

  for (int kb = 0; kb < 256; kb += 64) {
    const unsigned short* Asrc = (kb < 128) ? Agg : Hin;
    const unsigned short* ap = Asrc + (size_t)arow * 128 + (kb & 127) + sAk;
    unsigned short* al = &Als[sArow * LS + sAk];
    *(uint4*)(al + 0) = *(const uint4*)(ap + 0);
    *(uint4*)(al + 8) = *(const uint4*)(ap + 8);
    const unsigned short* bp = Wt + (size_t)sArow * 256 + kb + sAk;  // sArow = col here
    unsigned short* bl = &Bls[sArow * LS + sAk];
    *(uint4*)(bl + 0) = *(const uint4*)(bp + 0);
    *(uint4*)(bl + 8) = *(const uint4*)(bp + 8);
    __syncthreads();
#pragma unroll
    for (int ks = 0; ks < 64; ks += 32) {
      bf16x8 af[2], bfr[4];
#pragma unroll
      for (int i = 0; i < 2; ++i)
        af[i] = *(const bf16x8*)&Als[(wm + i * 16 + ln) * LS + ks + lh * 8];
#pragma unroll
      for (int j = 0; j < 4; ++j)
        bfr[j] = *(const bf16x8*)&Bls[(wn + j * 16 + ln) * LS + ks + lh * 8];
#pragma unroll
      for (int i = 0; i < 2; ++i)
#pragma unroll
        for (int j = 0; j < 4; ++j)
          acc[i][j] = __builtin_amdgcn_mfma_f32_16x16x32_bf16(af[i], bfr[j], acc[i][j], 0, 0, 0);
    }
    __syncthreads();
  }

  // epilogue: C/D map col=lane&15, row=(lane>>4)*4+reg  [m89/m91]
  const int lm = lane >> 4;
  float bc[4], b2c[4];
#pragma unroll
  for (int j = 0; j < 4; ++j) {
    int col = wn + j * 16 + ln;
    bc[j] = bvec[col];
    b2c[j] = bagg[col];
  }
#pragma unroll
  for (int i = 0; i < 2; ++i) {
    const int lr0 = wm + i * 16 + lm * 4;
#pragma unroll
    for (int r = 0; r < 4; ++r) {
      const int row = m0 + lr0 + r;
      if (row >= N_NODES) continue;
      const float swr = sw[row];
      const unsigned long long mw = maskw[(size_t)row * 2 + (wn >> 6)];
#pragma unroll
      for (int j = 0; j < 4; ++j) {
        const int col = wn + j * 16 + ln;
        float v = acc[i][j][r] + swr * bc[j] + b2c[j];
        v = fmaxf(v, 0.0f);
        v = ((mw >> (col & 63)) & 1ull) ? 2.0f * v : 0.0f;
        if (WF32) outf[(size_t)row * DGN + col] = v;
        if (MLP) tT[(lr0 + r) * LT + col] = f2bf(v);
        else outb[(size_t)row * DGN + col] = f2bf(v);
      }
    }
  }

  if (MLP) {
    __syncthreads();   // tT complete; Bls free for Tm1

    f32x4 acc2[2][4];
#pragma unroll
    for (int i = 0; i < 2; ++i)
#pragma unroll
      for (int j = 0; j < 4; ++j)
#pragma unroll
        for (int r = 0; r < 4; ++r) acc2[i][j][r] = 0.0f;

    for (int kb = 0; kb < 128; kb += 64) {
      const unsigned short* bp = Wt2 + (size_t)sArow * 128 + kb + sAk;
      unsigned short* bl = &Bls[sArow * LS + sAk];
      *(uint4*)(bl + 0) = *(const uint4*)(bp + 0);
      *(uint4*)(bl + 8) = *(const uint4*)(bp + 8);
      __syncthreads();
#pragma unroll
      for (int ks = 0; ks < 64; ks += 32) {
        bf16x8 af[2], bfr[4];
#pragma unroll
        for (int i = 0; i < 2; ++i)
          af[i] = *(const bf16x8*)&tT[(wm + i * 16 + ln) * LT + kb + ks + lh * 8];
#pragma unroll
        for (int j = 0; j < 4; ++j)
          bfr[j] = *(const bf16x8*)&Bls[(wn + j * 16 + ln) * LS + ks + lh * 8];
#pragma unroll
        for (int i = 0; i < 2; ++i)
#pragma unroll
          for (int j = 0; j < 4; ++j)
            acc2[i][j] = __builtin_amdgcn_mfma_f32_16x16x32_bf16(af[i], bfr[j], acc2[i][j], 0, 0, 0);
      }
      __syncthreads();
    }

    // epilogue2 -> t tile (overwrites tT; all A reads done)
    float bcol[4];
#pragma unroll
    for (int j = 0; j < 4; ++j) bcol[j] = b1[wn + j * 16 + ln];
#pragma unroll
    for (int i = 0; i < 2; ++i) {
      const int lr0 = wm + i * 16 + lm * 4;
#pragma unroll
      for (int r = 0; r < 4; ++r) {
        const int lr = lr0 + r;
#pragma unroll
        for (int j = 0; j < 4; ++j) {
          const int col = wn + j * 16 + ln;
          float v = fmaxf(acc2[i][j][r] + bcol[j], 0.0f);
          tT[lr * LT + col] = f2bf(v);
        }
      }
    }
    __syncthreads();

    // mlp2 via MFMA: wave w handles rows w*16..w*16+15, cols 0..15 (10 used)
    f32x4 acc3;
#pragma unroll
    for (int r = 0; r < 4; ++r) acc3[r] = 0.0f;
#pragma unroll
    for (int kt = 0; kt < 4; ++kt) {
      bf16x8 af = *(const bf16x8*)&tT[(wid * 16 + ln) * LT + kt * 32 + lh * 8];
      bf16x8 bw = *(const bf16x8*)&Wsb[ln * LT + kt * 32 + lh * 8];
      acc3 = __builtin_amdgcn_mfma_f32_16x16x32_bf16(af, bw, acc3, 0, 0, 0);
    }
    if (ln < DOUT) {
#pragma unroll
      for (int r = 0; r < 4; ++r) {
        const int row = m0 + wid * 16 + lm * 4 + r;
        if (row < N_NODES) y[(size_t)row * DOUT + ln] = acc3[r] + bs[ln];
      }
    }
  }
}

// ---------------------------------------------------------------------------
extern "C" void kernel_launch(void* const* d_in, const int* in_sizes, int n_in,
                              void* d_out, int out_size, void* d_ws, size_t ws_size,
                              hipStream_t stream) {
  const float* x        = (const float*)d_in[0];
  const int*   ei       = (const int*)d_in[1];
  const float* ew       = (const float*)d_in[2];
  const float* W_lin_in = (const float*)d_in[3];
  const float* b_lin_in = (const float*)d_in[4];
  const float* W_agg_in = (const float*)d_in[5];
  const float* b_agg_in = (const float*)d_in[6];
  const float* W_lin_h  = (const float*)d_in[7];
  const float* b_lin_h  = (const float*)d_in[8];
  const float* W_agg_h  = (const float*)d_in[9];
  const float* b_agg_h  = (const float*)d_in[10];
  const float* W_mlp1   = (const float*)d_in[11];
  const float* b_mlp1   = (const float*)d_in[12];
  const float* W_mlp2   = (const float*)d_in[13];
  const float* b_mlp2   = (const float*)d_in[14];

  float* hout = (float*)d_out;
  float* yout = hout + (size_t)NELEM;

  char* p = (char*)d_ws;
  auto alloc = [&](size_t bytes) {
    char* q = p;
    p += (bytes + 255) & ~(size_t)255;
    return q;
  };
  int*   chist   = (int*)alloc((size_t)(NBINS + 1) * 4);
  int*   ccursor = (int*)alloc((size_t)NBINS * 4);
  int*   rowptr  = (int*)alloc((size_t)(N_NODES + 1) * 4);
  float* invc    = (float*)alloc((size_t)N_NODES * 4);
  float* swv     = (float*)alloc((size_t)N_NODES * 4);
  uint2* pk      = (uint2*)alloc((size_t)NBINS * BSTR * 8);
  uint2* csr     = (uint2*)alloc((size_t)N_EDGES * 8);
  unsigned short* xb   = (unsigned short*)alloc((size_t)NELEM * 2);
  unsigned short* aggb = (unsigned short*)alloc((size_t)NELEM * 2);
  unsigned short* hA   = (unsigned short*)alloc((size_t)NELEM * 2);
  unsigned short* hB   = (unsigned short*)alloc((size_t)NELEM * 2);
  unsigned long long* mw0 = (unsigned long long*)alloc((size_t)NMASKW * 8);
  unsigned long long* mw1 = (unsigned long long*)alloc((size_t)NMASKW * 8);
  unsigned long long* mw2 = (unsigned long long*)alloc((size_t)NMASKW * 8);
  unsigned short* Tai = (unsigned short*)alloc(32768 * 2);
  unsigned short* Tah = (unsigned short*)alloc(32768 * 2);
  unsigned short* Tm1 = (unsigned short*)alloc(16384 * 2);
  float* bvi = (float*)alloc(128 * 4);
  float* bvh = (float*)alloc(128 * 4);

  unsigned dk[3][2];
  for (unsigned i = 0; i < 3; ++i) tf2x32(0u, 42u, 0u, i, dk[i][0], dk[i][1]);

  // ---- prep ----
  hipMemsetAsync(chist, 0, (size_t)(NBINS + 1) * 4, stream);
  hipMemsetAsync(ccursor, 0, (size_t)NBINS * 4, stream);
  mega_kernel<<<MEGA_BLOCKS, 256, 0, stream>>>(
      x, xb, W_lin_in, W_agg_in, W_lin_h, W_agg_h, W_mlp1,
      b_lin_in, b_lin_h, Tai, Tah, Tm1, bvi, bvh);

  // ---- CSR build (+ mw0 riders on scatter; hist merged into scatter) ----
  scatter_kernel<<<NTILES + MK_BLOCKS, 256, 0, stream>>>(
      ei, ew, ccursor, chist, pk, mw0, dk[0][0], dk[0][1]);
  place_kernel<<<NBINS, 256, 0, stream>>>(chist, pk, csr, rowptr, invc);

  // ---- layer 1 (+ mw1 riders on gemm1) ----
  agg_kernel<<<AB_BLOCKS, 256, 0, stream>>>(xb, rowptr, csr, invc, aggb, swv);
  layer_gemm<false, true, false><<<GB128 + MKB512, 512, 0, stream>>>(
      aggb, xb, Tai, bvi, b_agg_in, swv, mw0, nullptr, hA,
      mw1, dk[1][0], dk[1][1], nullptr, nullptr, nullptr, nullptr, nullptr);

  // ---- layer 2 (+ mw2 riders on gemm2) ----
  agg_kernel<<<AB_BLOCKS, 256, 0, stream>>>(hA, rowptr, csr, invc, aggb, nullptr);
  layer_gemm<false, true, false><<<GB128 + MKB512, 512, 0, stream>>>(
      aggb, hA, Tah, bvh, b_agg_h, swv, mw1, nullptr, hB,
      mw2, dk[2][0], dk[2][1], nullptr, nullptr, nullptr, nullptr, nullptr);

  // ---- layer 3 (mlp fused into gemm3, MFMA mlp2) ----
  agg_kernel<<<AB_BLOCKS, 256, 0, stream>>>(hB, rowptr, csr, invc, aggb, nullptr);
  layer_gemm<true, false, true><<<GB128, 512, 0, stream>>>(
      aggb, hB, Tah, bvh, b_agg_h, swv, mw2, hout, nullptr,
      nullptr, 0, 0, Tm1, b_mlp1, W_mlp2, b_mlp2, yout);
}